// Round 4
// baseline (110.574 us; speedup 1.0000x reference)
//
#include <hip/hip_runtime.h>
#include <hip/hip_bf16.h>

#define IN_F 4096
#define LOCAL_F 128
#define KSZ 64
#define STRIDE_ 32
#define FOLDS 127
#define BATCH_ 4096
#define OUT_F (FOLDS * LOCAL_F)    // 16256
#define WN (FOLDS * LOCAL_F * KSZ) // 1040384
#define XN (BATCH_ * IN_F)         // 16777216

typedef __attribute__((ext_vector_type(8))) short bf16x8;
typedef __attribute__((ext_vector_type(8))) unsigned short u16x8;
typedef __attribute__((ext_vector_type(4))) float f32x4;

__device__ __forceinline__ unsigned short f2bf(float f) {
    unsigned u = __builtin_bit_cast(unsigned, f);
    u += 0x7fffu + ((u >> 16) & 1u);   // round-to-nearest-even
    return (unsigned short)(u >> 16);
}

// ---- generic fp32 -> bf16 converter (8 elems/thread, n multiple of 8) ----
__global__ __launch_bounds__(256)
void cvt_kernel(const float* __restrict__ src, unsigned short* __restrict__ dst, int n) {
    int i = (blockIdx.x * 256 + threadIdx.x) * 8;
    if (i >= n) return;
    float4 a = *reinterpret_cast<const float4*>(src + i);
    float4 c = *reinterpret_cast<const float4*>(src + i + 4);
    u16x8 s;
    s[0] = f2bf(a.x); s[1] = f2bf(a.y); s[2] = f2bf(a.z); s[3] = f2bf(a.w);
    s[4] = f2bf(c.x); s[5] = f2bf(c.y); s[6] = f2bf(c.z); s[7] = f2bf(c.w);
    *reinterpret_cast<u16x8*>(dst + i) = s;
}

// ---- main: no LDS, no barrier; each wave = (fold, feature-half) x 64 batch rows ----
__global__ __launch_bounds__(256, 3)
void ll_main(const unsigned short* __restrict__ xbf,
             const unsigned short* __restrict__ Wbf,
             const float* __restrict__ b,
             float* __restrict__ out) {
    const int bg = blockIdx.x;           // 0..63
    const int fg = blockIdx.y;           // 0..63
    const int row0 = bg * 64;

    const int wave = threadIdx.x >> 6;
    const int lane = threadIdx.x & 63;
    const int fold = wave >> 1;
    const int h    = wave & 1;
    const int f = fg * 2 + fold;
    if (f >= FOLDS) return;              // no barriers anywhere: safe

    const int l16 = lane & 15;
    const int g   = lane >> 4;

    // ---- load all 16 fragments up-front (16 VMEM in flight) ----
    const unsigned short* Wf = Wbf + ((size_t)f * LOCAL_F + h * 64) * KSZ;
    const unsigned short* xw = xbf + (size_t)row0 * IN_F + f * STRIDE_;

    bf16x8 wf[2][4], af[2][4];
    #pragma unroll
    for (int ks = 0; ks < 2; ++ks) {
        #pragma unroll
        for (int nt = 0; nt < 4; ++nt)
            wf[ks][nt] = *reinterpret_cast<const bf16x8*>(Wf + (nt * 16 + l16) * KSZ + ks * 32 + g * 8);
        #pragma unroll
        for (int mt = 0; mt < 4; ++mt)
            af[ks][mt] = *reinterpret_cast<const bf16x8*>(xw + (size_t)(mt * 16 + l16) * IN_F + ks * 32 + g * 8);
    }

    f32x4 acc[4][4];
    #pragma unroll
    for (int mt = 0; mt < 4; ++mt)
        #pragma unroll
        for (int nt = 0; nt < 4; ++nt)
            acc[mt][nt] = (f32x4){0.f, 0.f, 0.f, 0.f};

    // D = W x X^T : lane holds D[feature = 4g+j][batch = l16]
    #pragma unroll
    for (int ks = 0; ks < 2; ++ks)
        #pragma unroll
        for (int mt = 0; mt < 4; ++mt)
            #pragma unroll
            for (int nt = 0; nt < 4; ++nt)
                acc[mt][nt] = __builtin_amdgcn_mfma_f32_16x16x32_bf16(wf[ks][nt], af[ks][mt], acc[mt][nt], 0, 0, 0);

    // ---- epilogue: bias + nontemporal float4 stores ----
    f32x4 bv[4];
    #pragma unroll
    for (int nt = 0; nt < 4; ++nt)
        bv[nt] = *reinterpret_cast<const f32x4*>(b + (size_t)f * LOCAL_F + h * 64 + nt * 16 + 4 * g);

    #pragma unroll
    for (int mt = 0; mt < 4; ++mt) {
        float* orow = out + (size_t)(row0 + mt * 16 + l16) * OUT_F + f * LOCAL_F + h * 64 + 4 * g;
        #pragma unroll
        for (int nt = 0; nt < 4; ++nt) {
            f32x4 v = acc[mt][nt] + bv[nt];
            __builtin_nontemporal_store(v, reinterpret_cast<f32x4*>(orow + nt * 16));
        }
    }
}

extern "C" void kernel_launch(void* const* d_in, const int* in_sizes, int n_in,
                              void* d_out, int out_size, void* d_ws, size_t ws_size,
                              hipStream_t stream) {
    const float* x = (const float*)d_in[0];
    const float* W = (const float*)d_in[1];
    const float* b = (const float*)d_in[2];
    float* out = (float*)d_out;

    unsigned short* xbf = (unsigned short*)d_ws;                  // 32 MB
    unsigned short* Wbf = (unsigned short*)d_ws + XN;             // +2 MB

    cvt_kernel<<<(XN / 8 + 255) / 256, 256, 0, stream>>>(x, xbf, XN);
    cvt_kernel<<<(WN / 8 + 255) / 256, 256, 0, stream>>>(W, Wbf, WN);

    dim3 grid(BATCH_ / 64, 64);
    ll_main<<<grid, 256, 0, stream>>>(xbf, Wbf, b, out);
}